// Round 6
// baseline (221733.447 us; speedup 1.0000x reference)
//
#include <hip/hip_runtime.h>
#include <math.h>

// Echo-state network scan — persistent 32-block gang, same-XCD L2 exchange.
//
// Placement: 256 blocks launched; gang = blockIdx%8==0 (rank b=blockIdx/8).
// Under round-robin block->XCD dispatch all 32 gang blocks land on one XCD,
// so per-step state exchange is coherent through that XCD's L2 with plain
// sc0 load/store (~200cy) instead of MALL-scope atomics (~1000cy).
//
// Hang-proofing (placement is a perf heuristic, NOT a correctness premise):
//  - Each gang block publishes its HW_REG_XCC_ID (device scope) into the
//    last out-row (zeroed at launch, only rewritten by the final-step
//    projection). All blocks poll all 32 nonzero slots -> identical sound
//    verdict "same_xcd".
//  - If scattered: writers add an sc0sc1 shadow store (write-through to
//    MALL) and pollers escalate to alternating sc1 loads -> correct, slow.
//
// Output: no atomicAdd (its MALL ack gated every step's barrier). Block b
// owns output dims {2b,2b+1}: waves 6-7 project step t-1 from the staged
// full state during phase B of step t (plain stores). Final row done in an
// epilogue. d_out needs no full memset (every element plainly stored).
//
// Workspace: exactly 16 KB = sbuf[2][1024] u64 packets (tag<<32|fp32 bits),
// zeroed per launch (tag 0 never matches want>=1).

#define G_LAUNCH 256
#define G_BLOCKS 32
#define ROWS     32     // W rows per gang block
#define TPB      512
#define KGROUPS  16     // TPB/32
#define KSPAN    64     // R_DIM/KGROUPS -> w[64]/thread, no spill
#define T_STEPS  32768
#define R_DIM    1024
#define IN_DIM   128
#define OUT_DIM  64

using ull = unsigned long long;

__device__ __forceinline__ ull ld_sc0(const ull* p) {
    ull v;
    asm volatile("global_load_dwordx2 %0, %1, off sc0\n\t"
                 "s_waitcnt vmcnt(0)"
                 : "=&v"(v) : "v"(p) : "memory");
    return v;
}
__device__ __forceinline__ ull ld_sc0sc1(const ull* p) {
    ull v;
    asm volatile("global_load_dwordx2 %0, %1, off sc0 sc1\n\t"
                 "s_waitcnt vmcnt(0)"
                 : "=&v"(v) : "v"(p) : "memory");
    return v;
}
__device__ __forceinline__ void st_sc0(ull* p, ull v) {
    asm volatile("global_store_dwordx2 %0, %1, off sc0" :: "v"(p), "v"(v) : "memory");
}
__device__ __forceinline__ void st_sc0sc1(ull* p, ull v) {
    asm volatile("global_store_dwordx2 %0, %1, off sc0 sc1" :: "v"(p), "v"(v) : "memory");
}

// Escalating poll: sc0 (local L2) first; after 24 misses alternate sc1
// (MALL view). Terminates in every placement given shadow stores exist for
// cross-L2 pairs; alternation keeps same-L2 pairs correct even if sc1 view
// is stale.
__device__ __forceinline__ ull repoll(const ull* p, int want) {
    ull v; int i = 0;
    do {
        ++i;
        v = (i > 24 && (i & 1)) ? ld_sc0sc1(p) : ld_sc0(p);
    } while ((int)(v >> 32) != want);
    return v;
}

__global__ __launch_bounds__(TPB, 1)
void esn_scan_kernel(const float* __restrict__ x,     // [T][128]
                     const float* __restrict__ Win,   // [1024][128]
                     const float* __restrict__ W,     // [1024][1024]
                     const float* __restrict__ Wout,  // [1024][64]
                     float* __restrict__ out,         // [T][64]
                     ull* __restrict__ sbuf)          // ws: [2][1024] u64
{
    constexpr float A   = 0.5f;   // leak rate
    constexpr float DEC = 0.5f;   // 1 - leak rate

    if (blockIdx.x & 7) return;               // non-gang: free the CU
    const int b    = blockIdx.x >> 3;         // rank 0..31
    const int tid  = threadIdx.x;
    const int lane = tid & 63;
    const int wave = tid >> 6;
    const int r    = tid & 31;
    const int kg   = tid >> 5;                // 0..15

    // ctl block = last out row (zeroed at launch; rewritten only by epilogue)
    int* xccbuf = (int*)(out + (size_t)T_STEPS * OUT_DIM - OUT_DIM);

    __shared__ int s_mode;
    if (tid == 0) {
        unsigned xcc = 0;
        asm volatile("s_getreg_b32 %0, hwreg(HW_REG_XCC_ID)" : "=s"(xcc));
        __hip_atomic_store(&xccbuf[b], (int)xcc + 1,
                           __ATOMIC_RELAXED, __HIP_MEMORY_SCOPE_AGENT);
        int x0 = 0, same = 1;
        for (int i = 0; i < G_BLOCKS; ++i) {
            int xi;
            do {
                xi = __hip_atomic_load(&xccbuf[i], __ATOMIC_RELAXED,
                                       __HIP_MEMORY_SCOPE_AGENT);
                if (!xi) __builtin_amdgcn_s_sleep(8);
            } while (!xi);
            if (i == 0) x0 = xi;
            same &= (xi == x0);
        }
        s_mode = same;
    }

    __shared__ __align__(16) float s_dec[R_DIM];     // (1-a)*s_{t-1}
    __shared__ float part[KGROUPS][ROWS];
    __shared__ float u_lds[2][ROWS];
    __shared__ float s_new_lds[ROWS];
    __shared__ __align__(16) float x_lds[2][IN_DIM];
    __shared__ __align__(16) float win_lds[ROWS * 132];
    __shared__ float wcolA[R_DIM], wcolB[R_DIM];     // Wout cols 2b, 2b+1

    // ---- one-time setup ----
    float w[KSPAN];
    {
        const float* wrow = W + ((size_t)(b * ROWS + r)) * R_DIM + kg * KSPAN;
        #pragma unroll
        for (int j = 0; j < KSPAN; j += 4) {
            const float4 v = *(const float4*)(wrow + j);
            w[j] = v.x; w[j+1] = v.y; w[j+2] = v.z; w[j+3] = v.w;
        }
    }
    for (int i = tid; i < ROWS * IN_DIM; i += TPB) {
        int rr = i >> 7, cc = i & 127;
        win_lds[rr * 132 + cc] = Win[((size_t)(b * ROWS + rr)) * IN_DIM + cc];
    }
    for (int i = tid; i < R_DIM; i += TPB) {
        wcolA[i] = Wout[(size_t)i * OUT_DIM + 2 * b];
        wcolB[i] = Wout[(size_t)i * OUT_DIM + 2 * b + 1];
        s_dec[i] = 0.0f;                       // s_{-1} = 0
    }
    if (tid < IN_DIM) {
        x_lds[0][tid] = x[tid];
        x_lds[1][tid] = x[IN_DIM + tid];
    }
    __syncthreads();
    const bool shadow = (s_mode == 0);         // scattered -> MALL shadows

    // u_0 by wave 1
    if (wave == 1) {
        int rr = lane & 31, kh = lane >> 5;
        float acc = 0.f;
        const float* wl = &win_lds[rr * 132 + kh * 64];
        const float* xl = &x_lds[0][kh * 64];
        #pragma unroll
        for (int i = 0; i < 64; i += 4) {
            float4 wv = *(const float4*)(wl + i);
            float4 xv = *(const float4*)(xl + i);
            acc += wv.x*xv.x + wv.y*xv.y + wv.z*xv.z + wv.w*xv.w;
        }
        acc += __shfl_down(acc, 32);
        if (lane < 32) u_lds[0][rr] = acc;
    }
    __syncthreads();

    ull pkt_reg = 0;   // wave0 lanes<32: last published packet (for shadow)

    // ---- main scan ----
    for (int t = 0; t < T_STEPS; ++t) {
        // Phase A: matvec partials. part[kg][r] = W[row][kg-span] . s_dec
        {
            float a0 = 0.f, a1 = 0.f, a2 = 0.f, a3 = 0.f;
            const float* sp = &s_dec[kg * KSPAN];
            #pragma unroll
            for (int j = 0; j < KSPAN; j += 4) {
                const float4 sv = *(const float4*)(sp + j);
                a0 += w[j]   * sv.x;
                a1 += w[j+1] * sv.y;
                a2 += w[j+2] * sv.z;
                a3 += w[j+3] * sv.w;
            }
            part[kg][r] = (a0 + a1) + (a2 + a3);
        }
        __syncthreads();

        // Phase B
        if (wave == 0) {
            // reduce 16 partials (8 per half-wave), finish step, publish sc0
            const int rr = lane & 31, half = lane >> 5;
            float tot = 0.f;
            #pragma unroll
            for (int k = 0; k < 8; ++k) tot += part[half * 8 + k][rr];
            tot += __shfl_down(tot, 32);
            if (lane < 32) {
                const float y  = u_lds[t & 1][lane] + tot;
                const float sd = s_dec[b * ROWS + lane];
                const float snew = sd + A * tanhf(y);
                pkt_reg = ((ull)(unsigned)(t + 1) << 32)
                        | (ull)__float_as_uint(snew);
                st_sc0(&sbuf[(size_t)(t & 1) * R_DIM + b * ROWS + lane], pkt_reg);
                s_new_lds[lane] = snew;
            }
        } else if (wave == 1 && t + 1 < T_STEPS) {
            // prefetch x_{t+2}; compute u_{t+1} (off critical path)
            const int tpre = (t + 2 < T_STEPS) ? (t + 2) : (T_STEPS - 1);
            const float xv0 = x[(size_t)tpre * IN_DIM + lane];
            const float xv1 = x[(size_t)tpre * IN_DIM + 64 + lane];
            int rr = lane & 31, kh = lane >> 5;
            float acc = 0.f;
            const float* wl = &win_lds[rr * 132 + kh * 64];
            const float* xl = &x_lds[(t + 1) & 1][kh * 64];
            #pragma unroll
            for (int i = 0; i < 64; i += 4) {
                float4 wv = *(const float4*)(wl + i);
                float4 xv = *(const float4*)(xl + i);
                acc += wv.x*xv.x + wv.y*xv.y + wv.z*xv.z + wv.w*xv.w;
            }
            acc += __shfl_down(acc, 32);
            if (lane < 32) u_lds[(t + 1) & 1][rr] = acc;
            x_lds[t & 1][lane]      = xv0;
            x_lds[t & 1][64 + lane] = xv1;
        } else if (wave >= 6 && t >= 1) {
            // project step t-1 onto this block's output dims (2b, 2b+1).
            // s_dec still holds s_{t-1}*DEC through phase B of step t.
            const float* wc = (wave == 6) ? wcolA : wcolB;
            float acc = 0.f;
            #pragma unroll
            for (int k = 0; k < 16; ++k)
                acc += s_dec[lane + 64 * k] * wc[lane + 64 * k];
            acc += __shfl_down(acc, 32);
            acc += __shfl_down(acc, 16);
            acc += __shfl_down(acc, 8);
            acc += __shfl_down(acc, 4);
            acc += __shfl_down(acc, 2);
            acc += __shfl_down(acc, 1);
            if (lane == 0)
                out[(size_t)(t - 1) * OUT_DIM + 2 * b + (wave - 6)] = 2.0f * acc;
        }
        __syncthreads();

        // Phase C: optional MALL shadow publish, then poll-stage s_t.
        if (shadow && wave == 0 && lane < 32)
            st_sc0sc1(&sbuf[(size_t)(t & 1) * R_DIM + b * ROWS + lane], pkt_reg);
        if (t + 1 < T_STEPS) {
            const int want = t + 1;
            ull* p0 = &sbuf[(size_t)(t & 1) * R_DIM + tid];
            ull* p1 = p0 + TPB;
            ull v0, v1;
            asm volatile("global_load_dwordx2 %0, %2, off sc0\n\t"
                         "global_load_dwordx2 %1, %3, off sc0\n\t"
                         "s_waitcnt vmcnt(0)"
                         : "=&v"(v0), "=&v"(v1)
                         : "v"(p0), "v"(p1) : "memory");
            if ((int)(v0 >> 32) != want) v0 = repoll(p0, want);
            if ((int)(v1 >> 32) != want) v1 = repoll(p1, want);
            s_dec[tid]       = __uint_as_float((unsigned)v0) * DEC;
            s_dec[TPB + tid] = __uint_as_float((unsigned)v1) * DEC;
        }
        __syncthreads();
    }

    // ---- epilogue: stage s_{T-1}, project final row ----
    {
        const int want = T_STEPS;                 // parity (T-1)&1 = 1
        ull* p0 = &sbuf[(size_t)R_DIM + tid];
        ull* p1 = p0 + TPB;
        ull v0 = ld_sc0(p0), v1 = ld_sc0(p1);
        if ((int)(v0 >> 32) != want) v0 = repoll(p0, want);
        if ((int)(v1 >> 32) != want) v1 = repoll(p1, want);
        s_dec[tid]       = __uint_as_float((unsigned)v0) * DEC;
        s_dec[TPB + tid] = __uint_as_float((unsigned)v1) * DEC;
        __syncthreads();
        if (wave >= 6) {
            const float* wc = (wave == 6) ? wcolA : wcolB;
            float acc = 0.f;
            #pragma unroll
            for (int k = 0; k < 16; ++k)
                acc += s_dec[lane + 64 * k] * wc[lane + 64 * k];
            acc += __shfl_down(acc, 32);
            acc += __shfl_down(acc, 16);
            acc += __shfl_down(acc, 8);
            acc += __shfl_down(acc, 4);
            acc += __shfl_down(acc, 2);
            acc += __shfl_down(acc, 1);
            if (lane == 0)
                out[(size_t)(T_STEPS - 1) * OUT_DIM + 2 * b + (wave - 6)] = 2.0f * acc;
        }
    }
}

extern "C" void kernel_launch(void* const* d_in, const int* in_sizes, int n_in,
                              void* d_out, int out_size, void* d_ws, size_t ws_size,
                              hipStream_t stream) {
    (void)in_sizes; (void)n_in; (void)ws_size;
    const float* x    = (const float*)d_in[0];   // input_data  [32768][128]
    const float* Win  = (const float*)d_in[1];   // input_weights [1024][128]
    const float* W    = (const float*)d_in[2];   // reservoir_weights [1024][1024]
    const float* Wout = (const float*)d_in[3];   // output_weights [1024][64]
    float* out = (float*)d_out;                  // [32768][64]
    ull* sbuf  = (ull*)d_ws;                     // exactly 16 KB used

    // zero packet tags (16 KB, within known ws footprint) and the ctl row
    // (last 64 floats of out; rewritten by the epilogue projection).
    hipMemsetAsync(d_ws, 0, 2 * (size_t)R_DIM * sizeof(ull), stream);
    hipMemsetAsync((char*)d_out
                       + ((size_t)out_size - OUT_DIM) * sizeof(float),
                   0, OUT_DIM * sizeof(float), stream);

    esn_scan_kernel<<<G_LAUNCH, TPB, 0, stream>>>(x, Win, W, Wout, out, sbuf);
}

// Round 10
// 46874.985 us; speedup vs baseline: 4.7303x; 4.7303x over previous
//
#include <hip/hip_runtime.h>
#include <math.h>

// Echo-state network scan — persistent 32-block gang, placement-agnostic.
//
// R9 fix: LLVM can't take uint4 as an inline-asm INPUT ("v") operand
// (128-bit indirect register input unsupported); uint4 OUTPUT ("=&v") and
// ull input both compile and ran in R6. So packets are published as 8-byte
// dwordx2 stores (one per lane, lanes 0..31) and polled as 16-byte dwordx4
// loads (two packets per thread).
//
// Design (R8): unconditionally live gang —
//   - gang = first 32 blocks to take a device-scope ticket, ANY XCD
//     (every ticket holder is executing -> gang always forms);
//   - members publish their XCC_ID into 32 ctl slots; all poll all 32
//     (bounded) -> identical verdict. Uniform -> sc0 (XCD L2) exchange;
//     scattered -> sc0 sc1 (MALL) exchange. No escalation, no spin-fallback.
// Structure validated in R6's passing run: ctl in last out row (memset 0,
// overwritten only by the epilogue); no atomicAdd on out — block b owns
// output dims {2b,2b+1}, waves 6-7 project step t-1 during phase B of step
// t (s_dec = s_{t-1}*0.5; the x2 in the store recovers it); wave 1
// prefetches x and computes u off the critical path; 512 thr -> w[64] in
// true VGPRs (no AGPR spill in the matvec).
//
// Workspace: exactly 16 KB = sbuf[2][1024] u64 packets, zeroed per launch.

#define G_LAUNCH 256
#define G_BLOCKS 32
#define ROWS     32     // W rows per gang block
#define TPB      512
#define KGROUPS  16     // TPB/32
#define KSPAN    64     // R_DIM/KGROUPS -> w[64]/thread
#define T_STEPS  32768
#define R_DIM    1024
#define IN_DIM   128
#define OUT_DIM  64

using ull = unsigned long long;

// 8B packet store; dev=true -> sc0 sc1 (MALL, device-coherent),
// dev=false -> sc0 (XCD L2, valid when all gang blocks share the XCD).
__device__ __forceinline__ void st8(ull* p, ull v, bool dev) {
    if (dev) asm volatile("global_store_dwordx2 %0, %1, off sc0 sc1"
                          :: "v"(p), "v"(v) : "memory");
    else     asm volatile("global_store_dwordx2 %0, %1, off sc0"
                          :: "v"(p), "v"(v) : "memory");
}
// 16B load = two adjacent packets {val0,tag0,val1,tag1}.
__device__ __forceinline__ uint4 ld16(const ull* p, bool dev) {
    uint4 v;
    if (dev) asm volatile("global_load_dwordx4 %0, %1, off sc0 sc1\n\t"
                          "s_waitcnt vmcnt(0)"
                          : "=&v"(v) : "v"(p) : "memory");
    else     asm volatile("global_load_dwordx4 %0, %1, off sc0\n\t"
                          "s_waitcnt vmcnt(0)"
                          : "=&v"(v) : "v"(p) : "memory");
    return v;
}

__global__ __launch_bounds__(TPB, 1)
void esn_scan_kernel(const float* __restrict__ x,     // [T][128]
                     const float* __restrict__ Win,   // [1024][128]
                     const float* __restrict__ W,     // [1024][1024]
                     const float* __restrict__ Wout,  // [1024][64]
                     float* __restrict__ out,         // [T][64]
                     ull* __restrict__ sbuf)          // ws: [2][1024] u64
{
    constexpr float A   = 0.5f;   // leak rate
    constexpr float DEC = 0.5f;   // 1 - leak rate

    const int tid  = threadIdx.x;
    const int lane = tid & 63;
    const int wave = tid >> 6;
    const int r    = tid & 31;
    const int kg   = tid >> 5;                // 0..15

    // ctl = last out row: [0..31]=xcc+1 per rank, [32]=ticket. Zeroed at
    // launch; overwritten only by the epilogue projection.
    int* ctl = (int*)(out + (size_t)T_STEPS * OUT_DIM - OUT_DIM);

    __shared__ int s_rank;
    __shared__ int s_mode;
    if (tid == 0) {
        const int tk = atomicAdd(&ctl[32], 1);        // device scope
        const int rk = (tk < G_BLOCKS) ? tk : -1;
        if (rk >= 0) {
            unsigned xcc = 0;
            asm volatile("s_getreg_b32 %0, hwreg(HW_REG_XCC_ID)" : "=s"(xcc));
            __hip_atomic_store(&ctl[rk], (int)xcc + 1,
                               __ATOMIC_RELAXED, __HIP_MEMORY_SCOPE_AGENT);
        }
        s_rank = rk;
    }
    __syncthreads();
    const int b = s_rank;
    if (b < 0) return;            // not in gang: free the CU

    // XCD-uniformity verdict (bounded: all 32 ticket holders are executing)
    if (tid == 0) {
        int x0 = 0, same = 1;
        for (int i = 0; i < G_BLOCKS; ++i) {
            int xi;
            do {
                xi = __hip_atomic_load(&ctl[i], __ATOMIC_RELAXED,
                                       __HIP_MEMORY_SCOPE_AGENT);
                if (!xi) __builtin_amdgcn_s_sleep(4);
            } while (!xi);
            if (i == 0) x0 = xi;
            same &= (xi == x0);
        }
        s_mode = same;
    }

    __shared__ __align__(16) float s_dec[R_DIM];     // (1-a)*s_{t-1}
    __shared__ float part[KGROUPS][ROWS];
    __shared__ float u_lds[2][ROWS];
    __shared__ __align__(16) float x_lds[2][IN_DIM];
    __shared__ __align__(16) float win_lds[ROWS * 132];
    __shared__ float wcolA[R_DIM], wcolB[R_DIM];     // Wout cols 2b, 2b+1

    // ---- one-time setup ----
    float w[KSPAN];   // W[b*32+r][kg*64 .. +63]
    {
        const float* wrow = W + ((size_t)(b * ROWS + r)) * R_DIM + kg * KSPAN;
        #pragma unroll
        for (int j = 0; j < KSPAN; j += 4) {
            const float4 v = *(const float4*)(wrow + j);
            w[j] = v.x; w[j+1] = v.y; w[j+2] = v.z; w[j+3] = v.w;
        }
    }
    for (int i = tid; i < ROWS * IN_DIM; i += TPB) {
        int rr = i >> 7, cc = i & 127;
        win_lds[rr * 132 + cc] = Win[((size_t)(b * ROWS + rr)) * IN_DIM + cc];
    }
    for (int i = tid; i < R_DIM; i += TPB) {
        wcolA[i] = Wout[(size_t)i * OUT_DIM + 2 * b];
        wcolB[i] = Wout[(size_t)i * OUT_DIM + 2 * b + 1];
        s_dec[i] = 0.0f;                       // s_{-1} = 0
    }
    if (tid < IN_DIM) {
        x_lds[0][tid] = x[tid];
        x_lds[1][tid] = x[IN_DIM + tid];
    }
    __syncthreads();
    const bool dev = (s_mode == 0);            // scattered -> MALL scope

    // u_0 by wave 1
    if (wave == 1) {
        int rr = lane & 31, kh = lane >> 5;
        float acc = 0.f;
        const float* wl = &win_lds[rr * 132 + kh * 64];
        const float* xl = &x_lds[0][kh * 64];
        #pragma unroll
        for (int i = 0; i < 64; i += 4) {
            float4 wv = *(const float4*)(wl + i);
            float4 xv = *(const float4*)(xl + i);
            acc += wv.x*xv.x + wv.y*xv.y + wv.z*xv.z + wv.w*xv.w;
        }
        acc += __shfl_down(acc, 32);
        if (lane < 32) u_lds[0][rr] = acc;
    }
    __syncthreads();

    // ---- main scan ----
    for (int t = 0; t < T_STEPS; ++t) {
        // Phase A: matvec partials. part[kg][r] = W[row][kg-span] . s_dec
        {
            float a0 = 0.f, a1 = 0.f, a2 = 0.f, a3 = 0.f;
            const float* sp = &s_dec[kg * KSPAN];
            #pragma unroll
            for (int j = 0; j < KSPAN; j += 4) {
                const float4 sv = *(const float4*)(sp + j);
                a0 += w[j]   * sv.x;
                a1 += w[j+1] * sv.y;
                a2 += w[j+2] * sv.z;
                a3 += w[j+3] * sv.w;
            }
            part[kg][r] = (a0 + a1) + (a2 + a3);
        }
        __syncthreads();

        // Phase B
        if (wave == 0) {
            // reduce 16 partials (8 per half-wave), finish step, publish
            const int rr = lane & 31, half = lane >> 5;
            float tot = 0.f;
            #pragma unroll
            for (int k = 0; k < 8; ++k) tot += part[half * 8 + k][rr];
            tot += __shfl_down(tot, 32);
            if (lane < 32) {
                const float y  = u_lds[t & 1][lane] + tot;
                const float sd = s_dec[b * ROWS + lane];
                const float snew = sd + A * tanhf(y);
                const ull pkt = ((ull)(unsigned)(t + 1) << 32)
                              | (ull)__float_as_uint(snew);
                st8(&sbuf[(size_t)(t & 1) * R_DIM + b * ROWS + lane], pkt, dev);
            }
        } else if (wave == 1 && t + 1 < T_STEPS) {
            // prefetch x_{t+2}; compute u_{t+1} (off critical path)
            const int tpre = (t + 2 < T_STEPS) ? (t + 2) : (T_STEPS - 1);
            const float xv0 = x[(size_t)tpre * IN_DIM + lane];
            const float xv1 = x[(size_t)tpre * IN_DIM + 64 + lane];
            int rr = lane & 31, kh = lane >> 5;
            float acc = 0.f;
            const float* wl = &win_lds[rr * 132 + kh * 64];
            const float* xl = &x_lds[(t + 1) & 1][kh * 64];
            #pragma unroll
            for (int i = 0; i < 64; i += 4) {
                float4 wv = *(const float4*)(wl + i);
                float4 xv = *(const float4*)(xl + i);
                acc += wv.x*xv.x + wv.y*xv.y + wv.z*xv.z + wv.w*xv.w;
            }
            acc += __shfl_down(acc, 32);
            if (lane < 32) u_lds[(t + 1) & 1][rr] = acc;
            x_lds[t & 1][lane]      = xv0;
            x_lds[t & 1][64 + lane] = xv1;
        } else if (wave >= 6 && t >= 1) {
            // project step t-1 onto dims {2b, 2b+1} (s_dec = s_{t-1}*DEC)
            const float* wc = (wave == 6) ? wcolA : wcolB;
            float acc = 0.f;
            #pragma unroll
            for (int k = 0; k < 16; ++k)
                acc += s_dec[lane + 64 * k] * wc[lane + 64 * k];
            acc += __shfl_down(acc, 32);
            acc += __shfl_down(acc, 16);
            acc += __shfl_down(acc, 8);
            acc += __shfl_down(acc, 4);
            acc += __shfl_down(acc, 2);
            acc += __shfl_down(acc, 1);
            if (lane == 0)
                out[(size_t)(t - 1) * OUT_DIM + 2 * b + (wave - 6)] = 2.0f * acc;
        }
        __syncthreads();

        // Phase C: poll-stage s_t. One 16B load = 2 adjacent packets;
        // s_sleep(1) backoff on miss.
        if (t + 1 < T_STEPS) {
            const unsigned want = (unsigned)(t + 1);
            const ull* p = &sbuf[(size_t)(t & 1) * R_DIM + 2 * tid];
            uint4 v = ld16(p, dev);
            while (v.y != want || v.w != want) {
                __builtin_amdgcn_s_sleep(1);
                v = ld16(p, dev);
            }
            s_dec[2 * tid]     = __uint_as_float(v.x) * DEC;
            s_dec[2 * tid + 1] = __uint_as_float(v.z) * DEC;
        }
        __syncthreads();
    }

    // ---- epilogue: stage s_{T-1}, project final row ----
    {
        const unsigned want = (unsigned)T_STEPS;   // parity (T-1)&1 = 1
        const ull* p = &sbuf[(size_t)R_DIM + 2 * tid];
        uint4 v = ld16(p, dev);
        while (v.y != want || v.w != want) {
            __builtin_amdgcn_s_sleep(1);
            v = ld16(p, dev);
        }
        s_dec[2 * tid]     = __uint_as_float(v.x) * DEC;
        s_dec[2 * tid + 1] = __uint_as_float(v.z) * DEC;
        __syncthreads();
        if (wave >= 6) {
            const float* wc = (wave == 6) ? wcolA : wcolB;
            float acc = 0.f;
            #pragma unroll
            for (int k = 0; k < 16; ++k)
                acc += s_dec[lane + 64 * k] * wc[lane + 64 * k];
            acc += __shfl_down(acc, 32);
            acc += __shfl_down(acc, 16);
            acc += __shfl_down(acc, 8);
            acc += __shfl_down(acc, 4);
            acc += __shfl_down(acc, 2);
            acc += __shfl_down(acc, 1);
            if (lane == 0)
                out[(size_t)(T_STEPS - 1) * OUT_DIM + 2 * b + (wave - 6)] = 2.0f * acc;
        }
    }
}

extern "C" void kernel_launch(void* const* d_in, const int* in_sizes, int n_in,
                              void* d_out, int out_size, void* d_ws, size_t ws_size,
                              hipStream_t stream) {
    (void)in_sizes; (void)n_in; (void)ws_size;
    const float* x    = (const float*)d_in[0];   // input_data  [32768][128]
    const float* Win  = (const float*)d_in[1];   // input_weights [1024][128]
    const float* W    = (const float*)d_in[2];   // reservoir_weights [1024][1024]
    const float* Wout = (const float*)d_in[3];   // output_weights [1024][64]
    float* out = (float*)d_out;                  // [32768][64]
    ull* sbuf  = (ull*)d_ws;                     // exactly 16 KB used

    // zero packet tags (16 KB, in-bounds) and the ctl row (last 64 floats
    // of out; rewritten by the epilogue projection).
    (void)hipMemsetAsync(d_ws, 0, 2 * (size_t)R_DIM * sizeof(ull), stream);
    (void)hipMemsetAsync((char*)d_out
                             + ((size_t)out_size - OUT_DIM) * sizeof(float),
                         0, OUT_DIM * sizeof(float), stream);

    esn_scan_kernel<<<G_LAUNCH, TPB, 0, stream>>>(x, Win, W, Wout, out, sbuf);
}